// Round 6
// baseline (101.561 us; speedup 1.0000x reference)
//
#include <hip/hip_runtime.h>
#include <math.h>

#define IH 1024
#define IW 1024
#define NPIX (IH * IW)
#define NW 16   // chunks
#define CH 64   // rows per chunk

#define FIX_DONE  0xF1DE0001u
#define SPEC_DONE 0x5EC0DE01u
#define T1_TOK    0x71AB1E01u
#define FLAG_STRIDE 64   // uints = 256 B between flag lines

// Relaxed agent-scope atomics: execute at the coherence point (LLC) -> cross-XCD
// visible without wbl2/inv. Verified R5 pattern.
#define AST(p_, v_) __hip_atomic_store((p_), (v_), __ATOMIC_RELAXED, __HIP_MEMORY_SCOPE_AGENT)
#define ALD(p_)     __hip_atomic_load((p_), __ATOMIC_RELAXED, __HIP_MEMORY_SCOPE_AGENT)

// async global->LDS: 64 lanes x 4B = 256 B = TWO consecutive 32-word rows
__device__ __forceinline__ void dma4(const unsigned int* g, unsigned int* l) {
    __builtin_amdgcn_global_load_lds(
        (const __attribute__((address_space(1))) void*)g,
        (__attribute__((address_space(3))) void*)l, 4, 0, 0);
}

// One row of the recurrence (verified absmax 0 since R8 of prior session).
#define CHAIN_STEP(W_, S_, T_)                                                  \
    unsigned int hxp = (prevU << 1) | prevU | ((prevU >> 1) | crp);             \
    unsigned int seed = hxp | (T_);                                             \
    unsigned int P = (W_);                                                      \
    unsigned int G = (S_) | (P & seed);                                         \
    unsigned int A = G | P;                                                     \
    unsigned int AXG = A ^ G;                                                   \
    unsigned int s1v = A + G;                                                   \
    unsigned long long gm = __ballot(s1v < A) & 0xFFFFFFFFull;                  \
    unsigned long long pm = __ballot(s1v == 0xFFFFFFFFu) & 0xFFFFFFFFull;       \
    unsigned long long G0 = __ballot((G & 1u) != 0u);                           \
    unsigned long long P0 = __ballot((P & 1u) != 0u);                           \
    unsigned long long aa = gm | pm;                                            \
    unsigned long long ssum = aa + gm;                                          \
    unsigned long long cvw = ssum ^ aa ^ gm;                                    \
    unsigned long long mlo_o = G0 | (P0 & cvw);                                 \
    unsigned int cin = (((unsigned int)cvw) >> k) & 1u;                         \
    unsigned int ovb = ((((unsigned int)(cvw >> 1)) >> k) & 1u) << 31;          \
    unsigned int s2 = s1v + cin;                                                \
    unsigned int outv = ((s2 ^ AXG) >> 1) | ovb;                                \
    unsigned int rtP = ((((unsigned int)(mlo_o >> 1)) >> k) & 1u) << 31;        \
    crp = cin | rtP;                                                            \
    prevU = outv;

// STAT_r = Rx(S_r) | Hx(S_{r+1})  (verified)
#define MKT(T_, SA_, SN_) {                                                     \
    unsigned long long mla = __ballot(((SA_) & 1u) != 0u);                      \
    unsigned long long mln = __ballot(((SN_) & 1u) != 0u);                      \
    unsigned long long mhn = __ballot(((SN_) >> 31) != 0u);                     \
    unsigned int rxC = (SA_) | ((SA_) >> 1)                                     \
                     | (((((unsigned int)(mla >> 1)) >> k) & 1u) << 31);        \
    unsigned int hxN = (SN_) | ((SN_) << 1) | ((SN_) >> 1)                      \
                     | ((((unsigned int)(mhn << 1)) >> k) & 1u)                 \
                     | (((((unsigned int)(mln >> 1)) >> k) & 1u) << 31);        \
    T_ = rxC | hxN; }

// One spec pass over the LDS-staged chunk. WRITE_: store rows to Osp (atomic).
// Needs in scope: Wl, Sl, Stail, r0, k, prevU, crp, SA, mloA, Osp.
#define SPEC_LOOP(WRITE_)                                                       \
    SA = Sl[0][k];                                                              \
    mloA = __ballot((SA & 1u) != 0u);                                           \
    _Pragma("unroll 2")                                                         \
    for (int d = 0; d < 64; ++d) {                                              \
        unsigned int Wv = Wl[d][k];                                             \
        unsigned int RS = (d < 63) ? Sl[d + 1][k] : Stail;                      \
        unsigned long long mhiN = __ballot((RS >> 31) != 0u);                   \
        unsigned long long mloN = __ballot((RS & 1u) != 0u);                    \
        unsigned int rxC = SA | (SA >> 1)                                       \
                         | (((((unsigned int)(mloA >> 1)) >> k) & 1u) << 31);   \
        unsigned int hxN = RS | (RS << 1) | (RS >> 1)                           \
                         | ((((unsigned int)(mhiN << 1)) >> k) & 1u)            \
                         | (((((unsigned int)(mloN >> 1)) >> k) & 1u) << 31);   \
        unsigned int Tv = rxC | hxN;                                            \
        CHAIN_STEP(Wv, SA, Tv)                                                  \
        if (WRITE_) { int r = r0 + d;                                           \
                      if (r <= 1022) AST(&Osp[r * 32 + k], outv); }             \
        SA = RS; mloA = mloN;                                                   \
    }

#define FIX_STEP(d, W_, S_, T_, SP_) if (!done) {                               \
    const int r = r0 + (d);                                                     \
    CHAIN_STEP(W_, S_, T_)                                                      \
    unsigned long long df = __ballot(outv != (SP_));                            \
    if ((df & 0xFFFFFFFFull) == 0ull) { done = true; converged = true; }        \
    else AST(&Osp[r * 32 + k], outv);                                           \
}

// ---------------- Stage 1+2+3 fused: gray -> Sobel -> NMS -> bit-packed ------
// (unchanged from the verified 96.5us version)
__global__ __launch_bounds__(256) void k_fused(const float* __restrict__ x,
                                               unsigned long long* __restrict__ Sp,
                                               unsigned long long* __restrict__ Wp) {
    __shared__ float g[20][72];
    __shared__ float m[18][68];
    const int bx = blockIdx.x & 15, by = blockIdx.x >> 4;
    const int tid = threadIdx.x;
    const int gi0 = by * 16 - 2, gj0 = bx * 64 - 2;

    for (int e = tid; e < 20 * 68; e += 256) {
        int ly = e / 68, lx = e - ly * 68;
        int gy = gi0 + ly, gxc = gj0 + lx;
        float v = 0.f;
        if ((unsigned)gy < (unsigned)IH && (unsigned)gxc < (unsigned)IW) {
            int p = gy * IW + gxc;
            float r = x[p], gg = x[NPIX + p], b = x[2 * NPIX + p];
            v = __fadd_rn(__fadd_rn(__fmul_rn(r, 0.2989f), __fmul_rn(gg, 0.587f)),
                          __fmul_rn(b, 0.114f));
        }
        g[ly][lx] = v;
    }
    __syncthreads();

    for (int e = tid; e < 18 * 66; e += 256) {
        int ly = e / 66, lx = e - ly * 66;
        float a00 = g[ly][lx],   a01 = g[ly][lx+1],   a02 = g[ly][lx+2];
        float a10 = g[ly+1][lx],                      a12 = g[ly+1][lx+2];
        float a20 = g[ly+2][lx], a21 = g[ly+2][lx+1], a22 = g[ly+2][lx+2];
        float gx = __fmul_rn(-1.f, a00);
        gx = __fadd_rn(gx, a02);
        gx = __fadd_rn(gx, __fmul_rn(-2.f, a10));
        gx = __fadd_rn(gx, __fmul_rn(2.f, a12));
        gx = __fadd_rn(gx, __fmul_rn(-1.f, a20));
        gx = __fadd_rn(gx, a22);
        float gy = a00;
        gy = __fadd_rn(gy, __fmul_rn(2.f, a01));
        gy = __fadd_rn(gy, a02);
        gy = __fadd_rn(gy, __fmul_rn(-1.f, a20));
        gy = __fadd_rn(gy, __fmul_rn(-2.f, a21));
        gy = __fadd_rn(gy, __fmul_rn(-1.f, a22));
        m[ly][lx] = __fsqrt_rn(__fadd_rn(__fmul_rn(gx, gx), __fmul_rn(gy, gy)));
    }
    __syncthreads();

    const int lane = tid & 63;
    const int wv = tid >> 6;
    #pragma unroll
    for (int rr = 0; rr < 4; ++rr) {
        int ti = wv * 4 + rr;
        int i = by * 16 + ti, j = bx * 64 + lane;
        float a00 = g[ti+1][lane+1], a01 = g[ti+1][lane+2], a02 = g[ti+1][lane+3];
        float a10 = g[ti+2][lane+1],                         a12 = g[ti+2][lane+3];
        float a20 = g[ti+3][lane+1], a21 = g[ti+3][lane+2], a22 = g[ti+3][lane+3];
        float gx = __fmul_rn(-1.f, a00);
        gx = __fadd_rn(gx, a02);
        gx = __fadd_rn(gx, __fmul_rn(-2.f, a10));
        gx = __fadd_rn(gx, __fmul_rn(2.f, a12));
        gx = __fadd_rn(gx, __fmul_rn(-1.f, a20));
        gx = __fadd_rn(gx, a22);
        float gy = a00;
        gy = __fadd_rn(gy, __fmul_rn(2.f, a01));
        gy = __fadd_rn(gy, a02);
        gy = __fadd_rn(gy, __fmul_rn(-1.f, a20));
        gy = __fadd_rn(gy, __fmul_rn(-2.f, a21));
        gy = __fadd_rn(gy, __fmul_rn(-1.f, a22));

        float ai = __fmul_rn(atan2f(gy, gx), 57.295779513082320876798154814105f);
        float c = m[ti+1][lane+1];
        float n1, n2;
        if (ai < -22.5f || ai >= 157.5f)      { n1 = m[ti+1][lane];   n2 = m[ti+1][lane+2]; }
        else if (ai < 22.5f)                  { n1 = m[ti][lane+1];   n2 = m[ti+2][lane+1]; }
        else if (ai < 67.5f)                  { n1 = m[ti][lane];     n2 = m[ti+2][lane+2]; }
        else if (ai < 112.5f)                 { n1 = m[ti][lane+1];   n2 = m[ti+2][lane+1]; }
        else                                  { n1 = m[ti][lane+2];   n2 = m[ti+2][lane];   }
        bool border = (i == 0) | (i == IH - 1) | (j == 0) | (j == IW - 1);
        bool keep = (c >= n1) && (c >= n2);
        float supp = keep ? c : 0.f;
        bool sb = !border && (supp >= 50.f);
        bool wb = !border && (supp >= 20.f) && !(supp >= 50.f);
        unsigned long long bs = __ballot(sb);
        unsigned long long bw = __ballot(wb);
        if (lane == 0) {
            Sp[i * 16 + bx] = bs;
            Wp[i * 16 + bx] = bw;
        }
    }
}

// =====================================================================
// Stage 4+5, R6: two-round speculation + all-LDS serial fix chain.
//   blocks 1..16 : spec chunk c=b-1 from LDS. Round 1: tail only ->
//                  publish T1[c]. Poll T1[c-1] (parallel exchange).
//                  Round 2: re-run seeded with T1[c-1], write Osp,
//                  publish T2[c] + SPEC_DONE[c]. Error of round-2 output
//                  requires a perturbation surviving a full 64-row chunk
//                  (decay ~<=20 rows) -> fix converges at row ~0.
//   block 0      : fix chain, 16 waves, ALL 15 handoffs intra-block LDS
//                  (verified R0 token pattern). Depth-16 register
//                  prestage; deep path via LLC atomics (rare). Drain
//                  (vmcnt0) BEFORE token pass: closes boundary-row race.
//   blocks 17..80: unpack consumers (verified R5 body).
// 81 blocks, all co-resident; spec c waits only on spec c-1 (lower id);
// fix/unpack wait on flags -> deadlock-free without cooperative launch.
// Flags ws-poison-safe: 0xAAAAAAAA != any token; value lines are gated.
// =====================================================================
__global__ __launch_bounds__(1024) void k_rest(const unsigned int* __restrict__ Sp,
                                               const unsigned int* __restrict__ Wp,
                                               unsigned int* __restrict__ Osp,
                                               float* __restrict__ out,
                                               unsigned int* __restrict__ flags) {
    __shared__ unsigned int Wl[64][32];      // 8 KB (spec blocks)
    __shared__ unsigned int Sl[64][32];      // 8 KB (spec blocks)
    __shared__ unsigned int prevLds[NW][32]; // fix block
    __shared__ unsigned int locTok;
    const int tid = threadIdx.x;
    const int b = (int)blockIdx.x;
    unsigned int* fixD  = flags;                       // 16 lines
    unsigned int* specD = flags + 16 * FLAG_STRIDE;    // 16 lines
    unsigned int* t1tok = flags + 32 * FLAG_STRIDE;    // 16 lines
    unsigned int* t1val = flags + 48 * FLAG_STRIDE;    // 16 lines (32 words each)
    unsigned int* t2val = flags + 64 * FLAG_STRIDE;    // 16 lines (32 words each)

    if (b >= 17) {
        // ---------------- unpack consumer: 16 rows per block ----------------
        const int bb = b - 16;                         // 1..64
        const unsigned int needChunk = (unsigned int)((16 * bb - 2) >> 6);
        if (tid == 0) {
            const unsigned int* f = fixD + needChunk * FLAG_STRIDE;
            while (ALD(f) != FIX_DONE)
                __builtin_amdgcn_s_sleep(8);
        }
        __syncthreads();
        __builtin_amdgcn_fence(__ATOMIC_ACQUIRE, "agent");  // inv stale lines
        const int px = ((bb - 1) * 1024 + tid) * 16;   // 16 px per thread
        unsigned int w = Osp[px >> 5];
        unsigned int bits = (w >> (px & 16)) & 0xFFFFu;
        float4* o = (float4*)(out + px);
        #pragma unroll
        for (int q = 0; q < 4; ++q) {
            float4 v;
            v.x = (bits & (1u << (4 * q + 0))) ? 1.f : 0.f;
            v.y = (bits & (1u << (4 * q + 1))) ? 1.f : 0.f;
            v.z = (bits & (1u << (4 * q + 2))) ? 1.f : 0.f;
            v.w = (bits & (1u << (4 * q + 3))) ? 1.f : 0.f;
            o[q] = v;
        }
        return;
    }

    if (b >= 1) {
        // ---------------- spec block: chunk c = b-1, one wave ----------------
        if (tid >= 64) return;                         // no barriers below
        const int lane = tid;
        const int k = lane & 31;
        const int c = b - 1;
        const int r0 = c * CH + 1;

        #pragma unroll
        for (int q = 0; q < 32; ++q) {
            dma4(Wp + (r0 + 2 * q) * 32 + lane, &Wl[2 * q][0]);
            dma4(Sp + (r0 + 2 * q) * 32 + lane, &Sl[2 * q][0]);
        }
        unsigned int prevU = Sp[(r0 - 1) * 32 + k];    // static lower bound
        int tl = r0 + 64; if (tl > 1023) tl = 1023;
        unsigned int Stail = Sp[tl * 32 + k];
        unsigned int crp;
        {
            unsigned long long mh = __ballot((prevU >> 31) != 0u);
            unsigned long long ml = __ballot((prevU & 1u) != 0u);
            crp = ((((unsigned int)(mh << 1)) >> k) & 1u)
                | (((((unsigned int)(ml >> 1)) >> k) & 1u) << 31);
        }
        if (c == 0 && lane < 32) AST(&Osp[k], 0u);     // border rows
        if (c == NW - 1 && lane < 32) AST(&Osp[1023 * 32 + k], 0u);
        asm volatile("s_waitcnt vmcnt(0)" ::: "memory");

        unsigned int SA;
        unsigned long long mloA;
        if (c == 0) {
            // single round: static seed IS exact for chunk 0 (verified)
            SPEC_LOOP(1)
            if (lane < 32) { AST(t1val + k, prevU); AST(t2val + k, prevU); }
            asm volatile("s_waitcnt vmcnt(0)" ::: "memory");
            if (lane == 0) { AST(t1tok, T1_TOK); AST(specD, SPEC_DONE); }
            return;
        }
        // round 1: tail only
        SPEC_LOOP(0)
        if (c < NW - 1) {
            if (lane < 32) AST(t1val + c * FLAG_STRIDE + k, prevU);
            asm volatile("s_waitcnt vmcnt(0)" ::: "memory");
            if (lane == 0) AST(t1tok + c * FLAG_STRIDE, T1_TOK);
        }
        // parallel exchange: seed from predecessor's round-1 tail
        {
            const unsigned int* tk = t1tok + (c - 1) * FLAG_STRIDE;
            while (ALD(tk) != T1_TOK)
                __builtin_amdgcn_s_sleep(1);
        }
        prevU = ALD(t1val + (c - 1) * FLAG_STRIDE + k);
        {
            unsigned long long mh = __ballot((prevU >> 31) != 0u);
            unsigned long long ml = __ballot((prevU & 1u) != 0u);
            crp = ((((unsigned int)(mh << 1)) >> k) & 1u)
                | (((((unsigned int)(ml >> 1)) >> k) & 1u) << 31);
        }
        // round 2: near-exact speculation, write Osp
        SPEC_LOOP(1)
        if (lane < 32) AST(t2val + c * FLAG_STRIDE + k, prevU);
        asm volatile("s_waitcnt vmcnt(0)" ::: "memory");
        if (lane == 0) AST(specD + c * FLAG_STRIDE, SPEC_DONE);
        return;
    }

    // ---------------- block 0: fix chain, 16 waves, all-LDS handoffs --------
    if (tid == 0) locTok = 0u;
    __syncthreads();
    const int wv = tid >> 6;
    const int lane = tid & 63;
    const int k = lane & 31;
    const int c = wv;
    const int r0 = c * CH + 1;

    if (c == 0) {
        // chunk 0 exact: relay its tail into the chain
        while (ALD(specD) != SPEC_DONE) __builtin_amdgcn_s_sleep(1);
        unsigned int bd = ALD(t2val + k);
        prevLds[1][k] = bd;
        asm volatile("s_waitcnt lgkmcnt(0)" ::: "memory");
        if (lane == 0) *((volatile unsigned int*)&locTok) = 1u;
        if (lane == 0) AST(fixD, FIX_DONE);
        return;
    }

    // prestage depth-16 (k_fused outputs: cross-kernel, normal loads) — this
    // overlaps the spec blocks' runtime entirely.
    const unsigned int* Sb = Sp + r0 * 32 + k;
    unsigned int S0 = Sb[0],    S1 = Sb[32],   S2 = Sb[64],   S3 = Sb[96],
                 S4 = Sb[128],  S5 = Sb[160],  S6 = Sb[192],  S7 = Sb[224],
                 S8 = Sb[256],  S9 = Sb[288],  S10 = Sb[320], S11 = Sb[352],
                 S12 = Sb[384], S13 = Sb[416], S14 = Sb[448], S15 = Sb[480],
                 S16 = Sb[512];
    const unsigned int* Wb = Wp + r0 * 32 + k;
    unsigned int W0 = Wb[0],    W1 = Wb[32],   W2 = Wb[64],   W3 = Wb[96],
                 W4 = Wb[128],  W5 = Wb[160],  W6 = Wb[192],  W7 = Wb[224],
                 W8 = Wb[256],  W9 = Wb[288],  W10 = Wb[320], W11 = Wb[352],
                 W12 = Wb[384], W13 = Wb[416], W14 = Wb[448], W15 = Wb[480];
    unsigned int T0, T1, T2, T3, T4, T5, T6, T7,
                 T8, T9, T10, T11, T12, T13, T14, T15;
    MKT(T0, S0, S1)   MKT(T1, S1, S2)   MKT(T2, S2, S3)   MKT(T3, S3, S4)
    MKT(T4, S4, S5)   MKT(T5, S5, S6)   MKT(T6, S6, S7)   MKT(T7, S7, S8)
    MKT(T8, S8, S9)   MKT(T9, S9, S10)  MKT(T10, S10, S11) MKT(T11, S11, S12)
    MKT(T12, S12, S13) MKT(T13, S13, S14) MKT(T14, S14, S15) MKT(T15, S15, S16)

    // wait for this chunk's round-2 spec, then prestage its outputs
    {
        const unsigned int* f = specD + c * FLAG_STRIDE;
        while (ALD(f) != SPEC_DONE) __builtin_amdgcn_s_sleep(2);
    }
    const unsigned int* Ob = Osp + r0 * 32 + k;
    unsigned int p0 = ALD(Ob + 0),    p1 = ALD(Ob + 32),   p2 = ALD(Ob + 64),
                 p3 = ALD(Ob + 96),   p4 = ALD(Ob + 128),  p5 = ALD(Ob + 160),
                 p6 = ALD(Ob + 192),  p7 = ALD(Ob + 224),  p8 = ALD(Ob + 256),
                 p9 = ALD(Ob + 288),  p10 = ALD(Ob + 320), p11 = ALD(Ob + 352),
                 p12 = ALD(Ob + 384), p13 = ALD(Ob + 416), p14 = ALD(Ob + 448),
                 p15 = ALD(Ob + 480);
    unsigned int p1last = ALD(t2val + c * FLAG_STRIDE + k);

    unsigned int bd = p1last;
    bool done = false, converged = false;
    unsigned int prevU = 0u, crp = 0u;

    // token spin (verified all-LDS chain)
    while (*((volatile unsigned int*)&locTok) != (unsigned int)c)
        __builtin_amdgcn_s_sleep(1);
    asm volatile("" ::: "memory");
    prevU = prevLds[c][k];                             // true tail of chunk c-1
    {
        unsigned long long mh = __ballot((prevU >> 31) != 0u);
        unsigned long long ml = __ballot((prevU & 1u) != 0u);
        crp = ((((unsigned int)(mh << 1)) >> k) & 1u)
            | (((((unsigned int)(ml >> 1)) >> k) & 1u) << 31);
    }
    FIX_STEP(0, W0, S0, T0, p0)     FIX_STEP(1, W1, S1, T1, p1)
    FIX_STEP(2, W2, S2, T2, p2)     FIX_STEP(3, W3, S3, T3, p3)
    FIX_STEP(4, W4, S4, T4, p4)     FIX_STEP(5, W5, S5, T5, p5)
    FIX_STEP(6, W6, S6, T6, p6)     FIX_STEP(7, W7, S7, T7, p7)
    FIX_STEP(8, W8, S8, T8, p8)     FIX_STEP(9, W9, S9, T9, p9)
    FIX_STEP(10, W10, S10, T10, p10) FIX_STEP(11, W11, S11, T11, p11)
    FIX_STEP(12, W12, S12, T12, p12) FIX_STEP(13, W13, S13, T13, p13)
    FIX_STEP(14, W14, S14, T14, p14) FIX_STEP(15, W15, S15, T15, p15)
    if (!done) {
        #pragma unroll 1
        for (int d = 16; d < CH; ++d) {                // ultra-rare deep path
            int r = r0 + d;
            if (r > 1022) break;
            unsigned int Wv = Wp[r * 32 + k];
            unsigned int Sv = Sp[r * 32 + k];
            int rn = r + 1; if (rn > 1023) rn = 1023;
            unsigned int Sn = Sp[rn * 32 + k];
            unsigned int sp = ALD(&Osp[r * 32 + k]);
            unsigned int Tv;
            MKT(Tv, Sv, Sn)
            CHAIN_STEP(Wv, Sv, Tv)
            unsigned long long df = __ballot(outv != sp);
            if ((df & 0xFFFFFFFFull) == 0ull) { converged = true; break; }
            AST(&Osp[r * 32 + k], outv);
        }
    }
    bd = converged ? p1last : prevU;                   // true row r0+63 either way

    // drain own fix stores BEFORE passing the token (closes boundary-row race)
    asm volatile("s_waitcnt vmcnt(0)" ::: "memory");
    if (c < NW - 1) prevLds[c + 1][k] = bd;
    asm volatile("s_waitcnt lgkmcnt(0)" ::: "memory");
    if (lane == 0) *((volatile unsigned int*)&locTok) = (unsigned int)(c + 1);
    if (lane == 0) AST(fixD + c * FLAG_STRIDE, FIX_DONE);
}

extern "C" void kernel_launch(void* const* d_in, const int* in_sizes, int n_in,
                              void* d_out, int out_size, void* d_ws, size_t ws_size,
                              hipStream_t stream) {
    const float* x = (const float*)d_in[0];
    float* out = (float*)d_out;
    char* ws = (char*)d_ws;

    unsigned long long* Sp = (unsigned long long*)(ws);
    unsigned long long* Wp = (unsigned long long*)(ws + 128u * 1024u);
    unsigned int*      Osp = (unsigned int*)(ws + 256u * 1024u);
    unsigned int*      flags = (unsigned int*)(ws + 1024u * 1024u);
    // flags poisoned 0xAAAAAAAA each iteration -> "not ready"; producers
    // write T1_TOK/SPEC_DONE/FIX_DONE in dependency order each launch.

    k_fused<<<1024, 256, 0, stream>>>(x, Sp, Wp);
    k_rest<<<81, 1024, 0, stream>>>((const unsigned int*)Sp,
                                    (const unsigned int*)Wp,
                                    Osp, out, flags);
}

// Round 7
// 87.067 us; speedup vs baseline: 1.1665x; 1.1665x over previous
//
#include <hip/hip_runtime.h>
#include <math.h>

#define IH 1024
#define IW 1024
#define NPIX (IH * IW)
#define NW 16    // fix chunks (64 rows)
#define CH 64
#define NSEG 32  // spec segments (32 rows)

#define T1_TOK    0x71AB1E01u
#define FLAG_STRIDE 64   // uints = 256 B between flag lines

// Relaxed agent-scope atomics (LLC coherence point) — verified R5/R6 pattern.
// Used ONLY for the T1 tail exchange inside k_spec2.
#define AST(p_, v_) __hip_atomic_store((p_), (v_), __ATOMIC_RELAXED, __HIP_MEMORY_SCOPE_AGENT)
#define ALD(p_)     __hip_atomic_load((p_), __ATOMIC_RELAXED, __HIP_MEMORY_SCOPE_AGENT)

// async global->LDS: 64 lanes x 4B = 256 B = TWO consecutive 32-word rows
__device__ __forceinline__ void dma4(const unsigned int* g, unsigned int* l) {
    __builtin_amdgcn_global_load_lds(
        (const __attribute__((address_space(1))) void*)g,
        (__attribute__((address_space(3))) void*)l, 4, 0, 0);
}

// One row of the recurrence (verified absmax 0 since R8 of prior session).
#define CHAIN_STEP(W_, S_, T_)                                                  \
    unsigned int hxp = (prevU << 1) | prevU | ((prevU >> 1) | crp);             \
    unsigned int seed = hxp | (T_);                                             \
    unsigned int P = (W_);                                                      \
    unsigned int G = (S_) | (P & seed);                                         \
    unsigned int A = G | P;                                                     \
    unsigned int AXG = A ^ G;                                                   \
    unsigned int s1v = A + G;                                                   \
    unsigned long long gm = __ballot(s1v < A) & 0xFFFFFFFFull;                  \
    unsigned long long pm = __ballot(s1v == 0xFFFFFFFFu) & 0xFFFFFFFFull;       \
    unsigned long long G0 = __ballot((G & 1u) != 0u);                           \
    unsigned long long P0 = __ballot((P & 1u) != 0u);                           \
    unsigned long long aa = gm | pm;                                            \
    unsigned long long ssum = aa + gm;                                          \
    unsigned long long cvw = ssum ^ aa ^ gm;                                    \
    unsigned long long mlo_o = G0 | (P0 & cvw);                                 \
    unsigned int cin = (((unsigned int)cvw) >> k) & 1u;                         \
    unsigned int ovb = ((((unsigned int)(cvw >> 1)) >> k) & 1u) << 31;          \
    unsigned int s2 = s1v + cin;                                                \
    unsigned int outv = ((s2 ^ AXG) >> 1) | ovb;                                \
    unsigned int rtP = ((((unsigned int)(mlo_o >> 1)) >> k) & 1u) << 31;        \
    crp = cin | rtP;                                                            \
    prevU = outv;

// STAT_r = Rx(S_r) | Hx(S_{r+1})  (verified)
#define MKT(T_, SA_, SN_) {                                                     \
    unsigned long long mla = __ballot(((SA_) & 1u) != 0u);                      \
    unsigned long long mln = __ballot(((SN_) & 1u) != 0u);                      \
    unsigned long long mhn = __ballot(((SN_) >> 31) != 0u);                     \
    unsigned int rxC = (SA_) | ((SA_) >> 1)                                     \
                     | (((((unsigned int)(mla >> 1)) >> k) & 1u) << 31);        \
    unsigned int hxN = (SN_) | ((SN_) << 1) | ((SN_) >> 1)                      \
                     | ((((unsigned int)(mhn << 1)) >> k) & 1u)                 \
                     | (((((unsigned int)(mln >> 1)) >> k) & 1u) << 31);        \
    T_ = rxC | hxN; }

#define CRP_FROM(PU_) {                                                         \
    unsigned long long mh = __ballot(((PU_) >> 31) != 0u);                      \
    unsigned long long ml = __ballot(((PU_) & 1u) != 0u);                       \
    crp = ((((unsigned int)(mh << 1)) >> k) & 1u)                               \
        | (((((unsigned int)(ml >> 1)) >> k) & 1u) << 31); }

// One 32-row spec pass over the LDS-staged segment (verified math).
// WRITE_: plain-store rows to Osp (consumers are in LATER kernels; the
// launch boundary provides visibility — verified R0 cross-kernel pattern).
#define SPEC_PASS(WRITE_)                                                       \
    SA = Sl[0][k];                                                              \
    mloA = __ballot((SA & 1u) != 0u);                                           \
    _Pragma("unroll 2")                                                         \
    for (int d = 0; d < 32; ++d) {                                              \
        unsigned int Wv = Wl[d][k];                                             \
        unsigned int RS = (d < 31) ? Sl[d + 1][k] : Stail;                      \
        unsigned long long mhiN = __ballot((RS >> 31) != 0u);                   \
        unsigned long long mloN = __ballot((RS & 1u) != 0u);                    \
        unsigned int rxC = SA | (SA >> 1)                                       \
                         | (((((unsigned int)(mloA >> 1)) >> k) & 1u) << 31);   \
        unsigned int hxN = RS | (RS << 1) | (RS >> 1)                           \
                         | ((((unsigned int)(mhiN << 1)) >> k) & 1u)            \
                         | (((((unsigned int)(mloN >> 1)) >> k) & 1u) << 31);   \
        unsigned int Tv = rxC | hxN;                                            \
        CHAIN_STEP(Wv, SA, Tv)                                                  \
        if (WRITE_) { int r = r0 + d;                                           \
                      if (r <= 1022) Osp[r * 32 + k] = outv; }                  \
        SA = RS; mloA = mloN;                                                   \
    }

#define FIX_STEP(d, W_, S_, T_, SP_) if (!done) {                               \
    const int r = r0 + (d);                                                     \
    CHAIN_STEP(W_, S_, T_)                                                      \
    unsigned long long df = __ballot(outv != (SP_));                            \
    if ((df & 0xFFFFFFFFull) == 0ull) { done = true; converged = true; }        \
    else Osp[r * 32 + k] = outv;                                                \
}

// ---------------- Stage 1+2+3 fused: gray -> Sobel -> NMS -> bit-packed ------
// (unchanged from the verified 96.5us version)
__global__ __launch_bounds__(256) void k_fused(const float* __restrict__ x,
                                               unsigned long long* __restrict__ Sp,
                                               unsigned long long* __restrict__ Wp) {
    __shared__ float g[20][72];
    __shared__ float m[18][68];
    const int bx = blockIdx.x & 15, by = blockIdx.x >> 4;
    const int tid = threadIdx.x;
    const int gi0 = by * 16 - 2, gj0 = bx * 64 - 2;

    for (int e = tid; e < 20 * 68; e += 256) {
        int ly = e / 68, lx = e - ly * 68;
        int gy = gi0 + ly, gxc = gj0 + lx;
        float v = 0.f;
        if ((unsigned)gy < (unsigned)IH && (unsigned)gxc < (unsigned)IW) {
            int p = gy * IW + gxc;
            float r = x[p], gg = x[NPIX + p], b = x[2 * NPIX + p];
            v = __fadd_rn(__fadd_rn(__fmul_rn(r, 0.2989f), __fmul_rn(gg, 0.587f)),
                          __fmul_rn(b, 0.114f));
        }
        g[ly][lx] = v;
    }
    __syncthreads();

    for (int e = tid; e < 18 * 66; e += 256) {
        int ly = e / 66, lx = e - ly * 66;
        float a00 = g[ly][lx],   a01 = g[ly][lx+1],   a02 = g[ly][lx+2];
        float a10 = g[ly+1][lx],                      a12 = g[ly+1][lx+2];
        float a20 = g[ly+2][lx], a21 = g[ly+2][lx+1], a22 = g[ly+2][lx+2];
        float gx = __fmul_rn(-1.f, a00);
        gx = __fadd_rn(gx, a02);
        gx = __fadd_rn(gx, __fmul_rn(-2.f, a10));
        gx = __fadd_rn(gx, __fmul_rn(2.f, a12));
        gx = __fadd_rn(gx, __fmul_rn(-1.f, a20));
        gx = __fadd_rn(gx, a22);
        float gy = a00;
        gy = __fadd_rn(gy, __fmul_rn(2.f, a01));
        gy = __fadd_rn(gy, a02);
        gy = __fadd_rn(gy, __fmul_rn(-1.f, a20));
        gy = __fadd_rn(gy, __fmul_rn(-2.f, a21));
        gy = __fadd_rn(gy, __fmul_rn(-1.f, a22));
        m[ly][lx] = __fsqrt_rn(__fadd_rn(__fmul_rn(gx, gx), __fmul_rn(gy, gy)));
    }
    __syncthreads();

    const int lane = tid & 63;
    const int wv = tid >> 6;
    #pragma unroll
    for (int rr = 0; rr < 4; ++rr) {
        int ti = wv * 4 + rr;
        int i = by * 16 + ti, j = bx * 64 + lane;
        float a00 = g[ti+1][lane+1], a01 = g[ti+1][lane+2], a02 = g[ti+1][lane+3];
        float a10 = g[ti+2][lane+1],                         a12 = g[ti+2][lane+3];
        float a20 = g[ti+3][lane+1], a21 = g[ti+3][lane+2], a22 = g[ti+3][lane+3];
        float gx = __fmul_rn(-1.f, a00);
        gx = __fadd_rn(gx, a02);
        gx = __fadd_rn(gx, __fmul_rn(-2.f, a10));
        gx = __fadd_rn(gx, __fmul_rn(2.f, a12));
        gx = __fadd_rn(gx, __fmul_rn(-1.f, a20));
        gx = __fadd_rn(gx, a22);
        float gy = a00;
        gy = __fadd_rn(gy, __fmul_rn(2.f, a01));
        gy = __fadd_rn(gy, a02);
        gy = __fadd_rn(gy, __fmul_rn(-1.f, a20));
        gy = __fadd_rn(gy, __fmul_rn(-2.f, a21));
        gy = __fadd_rn(gy, __fmul_rn(-1.f, a22));

        float ai = __fmul_rn(atan2f(gy, gx), 57.295779513082320876798154814105f);
        float c = m[ti+1][lane+1];
        float n1, n2;
        if (ai < -22.5f || ai >= 157.5f)      { n1 = m[ti+1][lane];   n2 = m[ti+1][lane+2]; }
        else if (ai < 22.5f)                  { n1 = m[ti][lane+1];   n2 = m[ti+2][lane+1]; }
        else if (ai < 67.5f)                  { n1 = m[ti][lane];     n2 = m[ti+2][lane+2]; }
        else if (ai < 112.5f)                 { n1 = m[ti][lane+1];   n2 = m[ti+2][lane+1]; }
        else                                  { n1 = m[ti][lane+2];   n2 = m[ti+2][lane];   }
        bool border = (i == 0) | (i == IH - 1) | (j == 0) | (j == IW - 1);
        bool keep = (c >= n1) && (c >= n2);
        float supp = keep ? c : 0.f;
        bool sb = !border && (supp >= 50.f);
        bool wb = !border && (supp >= 20.f) && !(supp >= 50.f);
        unsigned long long bs = __ballot(sb);
        unsigned long long bw = __ballot(wb);
        if (lane == 0) {
            Sp[i * 16 + bx] = bs;
            Wp[i * 16 + bx] = bw;
        }
    }
}

// =====================================================================
// Stage 4a, R7: two-round spec, 32 segments x 32 rows, own dispatch.
//   Round 1: static seed, 32 rows (decay ~15 => tail exact, 2x margin),
//            publish T1[j] via LLC atomics. All segments parallel.
//   Round 2: reseed with T1[j-1] (exact), rewrite 32 rows (plain stores;
//            later kernels see them via the launch boundary).
//   Segment 0: single exact pass (true-boundary seed, R0-verified).
// =====================================================================
__global__ __launch_bounds__(64, 1) void k_spec2(const unsigned int* __restrict__ Sp,
                                                 const unsigned int* __restrict__ Wp,
                                                 unsigned int* __restrict__ Osp,
                                                 unsigned int* __restrict__ flags) {
    __shared__ unsigned int Wl[32][32];   // 4 KB
    __shared__ unsigned int Sl[32][32];   // 4 KB
    const int lane = (int)threadIdx.x;
    const int k = lane & 31;
    const int j = (int)blockIdx.x;                     // segment 0..31
    const int r0 = j * 32 + 1;
    unsigned int* t1tok = flags;                       // 32 lines
    unsigned int* t1val = flags + 32 * FLAG_STRIDE;    // 32 lines

    #pragma unroll
    for (int q = 0; q < 16; ++q) {
        dma4(Wp + (r0 + 2 * q) * 32 + lane, &Wl[2 * q][0]);
        dma4(Sp + (r0 + 2 * q) * 32 + lane, &Sl[2 * q][0]);
    }
    unsigned int prevU = Sp[(r0 - 1) * 32 + k];        // static lower bound
    int tl = r0 + 32; if (tl > 1023) tl = 1023;
    unsigned int Stail = Sp[tl * 32 + k];
    unsigned int crp;
    CRP_FROM(prevU)
    if (j == 0 && lane < 32) Osp[k] = 0u;              // border rows
    if (j == NSEG - 1 && lane < 32) Osp[1023 * 32 + k] = 0u;
    asm volatile("s_waitcnt vmcnt(0)" ::: "memory");   // staging complete

    unsigned int SA;
    unsigned long long mloA;
    if (j == 0) {
        // true-boundary seed -> exact in one pass (R0-verified reasoning)
        SPEC_PASS(1)
        if (lane < 32) AST(t1val + k, prevU);
        asm volatile("s_waitcnt vmcnt(0)" ::: "memory");
        if (lane == 0) AST(t1tok, T1_TOK);
        return;
    }
    // round 1: tail only (no writes)
    SPEC_PASS(0)
    if (j < NSEG - 1) {
        if (lane < 32) AST(t1val + j * FLAG_STRIDE + k, prevU);
        asm volatile("s_waitcnt vmcnt(0)" ::: "memory");
        if (lane == 0) AST(t1tok + j * FLAG_STRIDE, T1_TOK);
    }
    // parallel exchange: seed from predecessor's round-1 tail (exact)
    {
        const unsigned int* tk = t1tok + (j - 1) * FLAG_STRIDE;
        while (ALD(tk) != T1_TOK) __builtin_amdgcn_s_sleep(1);
    }
    prevU = ALD(t1val + (j - 1) * FLAG_STRIDE + k);
    CRP_FROM(prevU)
    // round 2: exact speculation, write Osp
    SPEC_PASS(1)
}

// =====================================================================
// Stage 4b, R7: serial fix chain — R0-verified structure (plain loads,
// cross-kernel visibility via launch boundary; intra-block LDS token
// chain), depth-16 register prestage + rare global deep path. With exact
// round-2 spec this converges at FIX_STEP(0) for every chunk.
// =====================================================================
__global__ __launch_bounds__(1024) void k_fix(const unsigned int* __restrict__ Sp,
                                              const unsigned int* __restrict__ Wp,
                                              unsigned int* __restrict__ Osp) {
    __shared__ unsigned int prevLds[NW][32];
    __shared__ unsigned int locTok;
    const int tid = threadIdx.x;
    if (tid == 0) locTok = 0u;
    __syncthreads();
    const int wv = tid >> 6;
    const int lane = tid & 63;
    const int k = lane & 31;
    const int c = wv;
    const int r0 = c * CH + 1;

    int lr = r0 + 63; if (lr > 1022) lr = 1022;
    unsigned int p1last = Osp[lr * 32 + k];            // spec row r0+63

    if (c == 0) {
        // chunk 0 spec exact (segments 0,1 both exactly seeded)
        prevLds[1][k] = p1last;
        asm volatile("s_waitcnt lgkmcnt(0)" ::: "memory");
        if (lane == 0) *((volatile unsigned int*)&locTok) = 1u;
        return;
    }

    // prestage depth-16 working set (overlaps predecessor chain time)
    const unsigned int* Sb = Sp + r0 * 32 + k;
    unsigned int S0 = Sb[0],    S1 = Sb[32],   S2 = Sb[64],   S3 = Sb[96],
                 S4 = Sb[128],  S5 = Sb[160],  S6 = Sb[192],  S7 = Sb[224],
                 S8 = Sb[256],  S9 = Sb[288],  S10 = Sb[320], S11 = Sb[352],
                 S12 = Sb[384], S13 = Sb[416], S14 = Sb[448], S15 = Sb[480],
                 S16 = Sb[512];
    const unsigned int* Wb = Wp + r0 * 32 + k;
    unsigned int W0 = Wb[0],    W1 = Wb[32],   W2 = Wb[64],   W3 = Wb[96],
                 W4 = Wb[128],  W5 = Wb[160],  W6 = Wb[192],  W7 = Wb[224],
                 W8 = Wb[256],  W9 = Wb[288],  W10 = Wb[320], W11 = Wb[352],
                 W12 = Wb[384], W13 = Wb[416], W14 = Wb[448], W15 = Wb[480];
    const unsigned int* Ob = Osp + r0 * 32 + k;
    unsigned int p0 = Ob[0],    p1 = Ob[32],   p2 = Ob[64],   p3 = Ob[96],
                 p4 = Ob[128],  p5 = Ob[160],  p6 = Ob[192],  p7 = Ob[224],
                 p8 = Ob[256],  p9 = Ob[288],  p10 = Ob[320], p11 = Ob[352],
                 p12 = Ob[384], p13 = Ob[416], p14 = Ob[448], p15 = Ob[480];
    unsigned int T0, T1, T2, T3, T4, T5, T6, T7,
                 T8, T9, T10, T11, T12, T13, T14, T15;
    MKT(T0, S0, S1)    MKT(T1, S1, S2)    MKT(T2, S2, S3)    MKT(T3, S3, S4)
    MKT(T4, S4, S5)    MKT(T5, S5, S6)    MKT(T6, S6, S7)    MKT(T7, S7, S8)
    MKT(T8, S8, S9)    MKT(T9, S9, S10)   MKT(T10, S10, S11) MKT(T11, S11, S12)
    MKT(T12, S12, S13) MKT(T13, S13, S14) MKT(T14, S14, S15) MKT(T15, S15, S16)

    unsigned int bd = p1last;
    bool done = false, converged = false;
    unsigned int prevU = 0u, crp = 0u;

    // token spin (verified all-LDS chain)
    while (*((volatile unsigned int*)&locTok) != (unsigned int)c)
        __builtin_amdgcn_s_sleep(1);
    asm volatile("" ::: "memory");
    prevU = prevLds[c][k];                             // true tail of chunk c-1
    CRP_FROM(prevU)
    FIX_STEP(0, W0, S0, T0, p0)      FIX_STEP(1, W1, S1, T1, p1)
    FIX_STEP(2, W2, S2, T2, p2)      FIX_STEP(3, W3, S3, T3, p3)
    FIX_STEP(4, W4, S4, T4, p4)      FIX_STEP(5, W5, S5, T5, p5)
    FIX_STEP(6, W6, S6, T6, p6)      FIX_STEP(7, W7, S7, T7, p7)
    FIX_STEP(8, W8, S8, T8, p8)      FIX_STEP(9, W9, S9, T9, p9)
    FIX_STEP(10, W10, S10, T10, p10) FIX_STEP(11, W11, S11, T11, p11)
    FIX_STEP(12, W12, S12, T12, p12) FIX_STEP(13, W13, S13, T13, p13)
    FIX_STEP(14, W14, S14, T14, p14) FIX_STEP(15, W15, S15, T15, p15)
    if (!done) {
        #pragma unroll 1
        for (int d = 16; d < CH; ++d) {                // rare deep path
            int r = r0 + d;
            if (r > 1022) break;
            unsigned int Wv = Wp[r * 32 + k];
            unsigned int Sv = Sp[r * 32 + k];
            int rn = r + 1; if (rn > 1023) rn = 1023;
            unsigned int Sn = Sp[rn * 32 + k];
            unsigned int sp = Osp[r * 32 + k];
            unsigned int Tv;
            MKT(Tv, Sv, Sn)
            CHAIN_STEP(Wv, Sv, Tv)
            unsigned long long df = __ballot(outv != sp);
            if ((df & 0xFFFFFFFFull) == 0ull) { converged = true; break; }
            Osp[r * 32 + k] = outv;
        }
    }
    bd = converged ? p1last : prevU;                   // true row r0+63 either way

    // drain own stores before passing the token
    asm volatile("s_waitcnt vmcnt(0)" ::: "memory");
    if (c < NW - 1) prevLds[c + 1][k] = bd;
    asm volatile("s_waitcnt lgkmcnt(0)" ::: "memory");
    if (lane == 0) *((volatile unsigned int*)&locTok) = (unsigned int)(c + 1);
}

// ---------------- Stage 5: unpack bits -> float (verified R0 body) -----------
__global__ __launch_bounds__(256) void k_unpack(const unsigned int* __restrict__ Osp,
                                                float* __restrict__ out) {
    int t = blockIdx.x * blockDim.x + threadIdx.x;   // 1 thread = 4 px
    int px = t * 4;
    if (px >= NPIX) return;
    unsigned int w = Osp[px >> 5];
    int sh = px & 31;
    float4 v;
    v.x = ((w >> (sh + 0)) & 1u) ? 1.f : 0.f;
    v.y = ((w >> (sh + 1)) & 1u) ? 1.f : 0.f;
    v.z = ((w >> (sh + 2)) & 1u) ? 1.f : 0.f;
    v.w = ((w >> (sh + 3)) & 1u) ? 1.f : 0.f;
    *((float4*)(out + px)) = v;
}

extern "C" void kernel_launch(void* const* d_in, const int* in_sizes, int n_in,
                              void* d_out, int out_size, void* d_ws, size_t ws_size,
                              hipStream_t stream) {
    const float* x = (const float*)d_in[0];
    float* out = (float*)d_out;
    char* ws = (char*)d_ws;

    unsigned long long* Sp = (unsigned long long*)(ws);
    unsigned long long* Wp = (unsigned long long*)(ws + 128u * 1024u);
    unsigned int*      Osp = (unsigned int*)(ws + 256u * 1024u);
    unsigned int*      flags = (unsigned int*)(ws + 1024u * 1024u);
    // flags poisoned 0xAAAAAAAA each iteration -> "not ready"; spec blocks
    // write T1_TOK in dependency order each launch.

    k_fused<<<1024, 256, 0, stream>>>(x, Sp, Wp);
    k_spec2<<<NSEG, 64, 0, stream>>>((const unsigned int*)Sp,
                                     (const unsigned int*)Wp, Osp, flags);
    k_fix<<<1, 1024, 0, stream>>>((const unsigned int*)Sp,
                                  (const unsigned int*)Wp, Osp);
    k_unpack<<<1024, 256, 0, stream>>>((const unsigned int*)Osp, out);
}

// Round 8
// 87.027 us; speedup vs baseline: 1.1670x; 1.0005x over previous
//
#include <hip/hip_runtime.h>
#include <math.h>

#define IH 1024
#define IW 1024
#define NPIX (IH * IW)
#define NW 16    // fix chunks (64 rows)
#define CH 64
#define NSEG 32  // spec segments (32 rows)

#define T1_TOK    0x71AB1E01u
#define FIX_DONE  0xF1DE0001u
#define FLAG_STRIDE 64   // uints = 256 B between flag lines

// Relaxed agent-scope atomics (LLC coherence point) — verified R5/R6/R7 pattern.
#define AST(p_, v_) __hip_atomic_store((p_), (v_), __ATOMIC_RELAXED, __HIP_MEMORY_SCOPE_AGENT)
#define ALD(p_)     __hip_atomic_load((p_), __ATOMIC_RELAXED, __HIP_MEMORY_SCOPE_AGENT)

// async global->LDS: 64 lanes x 4B = 256 B = TWO consecutive 32-word rows
__device__ __forceinline__ void dma4(const unsigned int* g, unsigned int* l) {
    __builtin_amdgcn_global_load_lds(
        (const __attribute__((address_space(1))) void*)g,
        (__attribute__((address_space(3))) void*)l, 4, 0, 0);
}

// One row of the recurrence (verified absmax 0 since R8 of prior session).
#define CHAIN_STEP(W_, S_, T_)                                                  \
    unsigned int hxp = (prevU << 1) | prevU | ((prevU >> 1) | crp);             \
    unsigned int seed = hxp | (T_);                                             \
    unsigned int P = (W_);                                                      \
    unsigned int G = (S_) | (P & seed);                                         \
    unsigned int A = G | P;                                                     \
    unsigned int AXG = A ^ G;                                                   \
    unsigned int s1v = A + G;                                                   \
    unsigned long long gm = __ballot(s1v < A) & 0xFFFFFFFFull;                  \
    unsigned long long pm = __ballot(s1v == 0xFFFFFFFFu) & 0xFFFFFFFFull;       \
    unsigned long long G0 = __ballot((G & 1u) != 0u);                           \
    unsigned long long P0 = __ballot((P & 1u) != 0u);                           \
    unsigned long long aa = gm | pm;                                            \
    unsigned long long ssum = aa + gm;                                          \
    unsigned long long cvw = ssum ^ aa ^ gm;                                    \
    unsigned long long mlo_o = G0 | (P0 & cvw);                                 \
    unsigned int cin = (((unsigned int)cvw) >> k) & 1u;                         \
    unsigned int ovb = ((((unsigned int)(cvw >> 1)) >> k) & 1u) << 31;          \
    unsigned int s2 = s1v + cin;                                                \
    unsigned int outv = ((s2 ^ AXG) >> 1) | ovb;                                \
    unsigned int rtP = ((((unsigned int)(mlo_o >> 1)) >> k) & 1u) << 31;        \
    crp = cin | rtP;                                                            \
    prevU = outv;

// STAT_r = Rx(S_r) | Hx(S_{r+1})  (verified)
#define MKT(T_, SA_, SN_) {                                                     \
    unsigned long long mla = __ballot(((SA_) & 1u) != 0u);                      \
    unsigned long long mln = __ballot(((SN_) & 1u) != 0u);                      \
    unsigned long long mhn = __ballot(((SN_) >> 31) != 0u);                     \
    unsigned int rxC = (SA_) | ((SA_) >> 1)                                     \
                     | (((((unsigned int)(mla >> 1)) >> k) & 1u) << 31);        \
    unsigned int hxN = (SN_) | ((SN_) << 1) | ((SN_) >> 1)                      \
                     | ((((unsigned int)(mhn << 1)) >> k) & 1u)                 \
                     | (((((unsigned int)(mln >> 1)) >> k) & 1u) << 31);        \
    T_ = rxC | hxN; }

#define CRP_FROM(PU_) {                                                         \
    unsigned long long mh = __ballot(((PU_) >> 31) != 0u);                      \
    unsigned long long ml = __ballot(((PU_) & 1u) != 0u);                       \
    crp = ((((unsigned int)(mh << 1)) >> k) & 1u)                               \
        | (((((unsigned int)(ml >> 1)) >> k) & 1u) << 31); }

// 32-row spec pass over the LDS-staged segment (verified math).
// WRITE_OSP_: plain-store rows to Osp (consumers in later kernels; launch
// boundary provides visibility). WRITE_PL_: also record rows in LDS Pl
// (round-2 convergence reference).
#define SPEC_PASS(WRITE_OSP_, WRITE_PL_)                                        \
    SA = Sl[0][k];                                                              \
    mloA = __ballot((SA & 1u) != 0u);                                           \
    _Pragma("unroll 2")                                                         \
    for (int d = 0; d < 32; ++d) {                                              \
        unsigned int Wv = Wl[d][k];                                             \
        unsigned int RS = (d < 31) ? Sl[d + 1][k] : Stail;                      \
        unsigned long long mhiN = __ballot((RS >> 31) != 0u);                   \
        unsigned long long mloN = __ballot((RS & 1u) != 0u);                    \
        unsigned int rxC = SA | (SA >> 1)                                       \
                         | (((((unsigned int)(mloA >> 1)) >> k) & 1u) << 31);   \
        unsigned int hxN = RS | (RS << 1) | (RS >> 1)                           \
                         | ((((unsigned int)(mhiN << 1)) >> k) & 1u)            \
                         | (((((unsigned int)(mloN >> 1)) >> k) & 1u) << 31);   \
        unsigned int Tv = rxC | hxN;                                            \
        CHAIN_STEP(Wv, SA, Tv)                                                  \
        if (WRITE_PL_) Pl[d][k] = outv;                                         \
        if (WRITE_OSP_) { int r = r0 + d;                                       \
                          if (r <= 1022) Osp[r * 32 + k] = outv; }              \
        SA = RS; mloA = mloN;                                                   \
    }

#define FIX_STEP(d, W_, S_, T_, SP_) if (!done) {                               \
    const int r = r0 + (d);                                                     \
    CHAIN_STEP(W_, S_, T_)                                                      \
    unsigned long long df = __ballot(outv != (SP_));                            \
    if ((df & 0xFFFFFFFFull) == 0ull) { done = true; converged = true; }        \
    else AST(&Osp[r * 32 + k], outv);                                           \
}

// ---------------- Stage 1+2+3 fused: gray -> Sobel -> NMS -> bit-packed ------
// (unchanged from the verified 96.5us version)
__global__ __launch_bounds__(256) void k_fused(const float* __restrict__ x,
                                               unsigned long long* __restrict__ Sp,
                                               unsigned long long* __restrict__ Wp) {
    __shared__ float g[20][72];
    __shared__ float m[18][68];
    const int bx = blockIdx.x & 15, by = blockIdx.x >> 4;
    const int tid = threadIdx.x;
    const int gi0 = by * 16 - 2, gj0 = bx * 64 - 2;

    for (int e = tid; e < 20 * 68; e += 256) {
        int ly = e / 68, lx = e - ly * 68;
        int gy = gi0 + ly, gxc = gj0 + lx;
        float v = 0.f;
        if ((unsigned)gy < (unsigned)IH && (unsigned)gxc < (unsigned)IW) {
            int p = gy * IW + gxc;
            float r = x[p], gg = x[NPIX + p], b = x[2 * NPIX + p];
            v = __fadd_rn(__fadd_rn(__fmul_rn(r, 0.2989f), __fmul_rn(gg, 0.587f)),
                          __fmul_rn(b, 0.114f));
        }
        g[ly][lx] = v;
    }
    __syncthreads();

    for (int e = tid; e < 18 * 66; e += 256) {
        int ly = e / 66, lx = e - ly * 66;
        float a00 = g[ly][lx],   a01 = g[ly][lx+1],   a02 = g[ly][lx+2];
        float a10 = g[ly+1][lx],                      a12 = g[ly+1][lx+2];
        float a20 = g[ly+2][lx], a21 = g[ly+2][lx+1], a22 = g[ly+2][lx+2];
        float gx = __fmul_rn(-1.f, a00);
        gx = __fadd_rn(gx, a02);
        gx = __fadd_rn(gx, __fmul_rn(-2.f, a10));
        gx = __fadd_rn(gx, __fmul_rn(2.f, a12));
        gx = __fadd_rn(gx, __fmul_rn(-1.f, a20));
        gx = __fadd_rn(gx, a22);
        float gy = a00;
        gy = __fadd_rn(gy, __fmul_rn(2.f, a01));
        gy = __fadd_rn(gy, a02);
        gy = __fadd_rn(gy, __fmul_rn(-1.f, a20));
        gy = __fadd_rn(gy, __fmul_rn(-2.f, a21));
        gy = __fadd_rn(gy, __fmul_rn(-1.f, a22));
        m[ly][lx] = __fsqrt_rn(__fadd_rn(__fmul_rn(gx, gx), __fmul_rn(gy, gy)));
    }
    __syncthreads();

    const int lane = tid & 63;
    const int wv = tid >> 6;
    #pragma unroll
    for (int rr = 0; rr < 4; ++rr) {
        int ti = wv * 4 + rr;
        int i = by * 16 + ti, j = bx * 64 + lane;
        float a00 = g[ti+1][lane+1], a01 = g[ti+1][lane+2], a02 = g[ti+1][lane+3];
        float a10 = g[ti+2][lane+1],                         a12 = g[ti+2][lane+3];
        float a20 = g[ti+3][lane+1], a21 = g[ti+3][lane+2], a22 = g[ti+3][lane+3];
        float gx = __fmul_rn(-1.f, a00);
        gx = __fadd_rn(gx, a02);
        gx = __fadd_rn(gx, __fmul_rn(-2.f, a10));
        gx = __fadd_rn(gx, __fmul_rn(2.f, a12));
        gx = __fadd_rn(gx, __fmul_rn(-1.f, a20));
        gx = __fadd_rn(gx, a22);
        float gy = a00;
        gy = __fadd_rn(gy, __fmul_rn(2.f, a01));
        gy = __fadd_rn(gy, a02);
        gy = __fadd_rn(gy, __fmul_rn(-1.f, a20));
        gy = __fadd_rn(gy, __fmul_rn(-2.f, a21));
        gy = __fadd_rn(gy, __fmul_rn(-1.f, a22));

        float ai = __fmul_rn(atan2f(gy, gx), 57.295779513082320876798154814105f);
        float c = m[ti+1][lane+1];
        float n1, n2;
        if (ai < -22.5f || ai >= 157.5f)      { n1 = m[ti+1][lane];   n2 = m[ti+1][lane+2]; }
        else if (ai < 22.5f)                  { n1 = m[ti][lane+1];   n2 = m[ti+2][lane+1]; }
        else if (ai < 67.5f)                  { n1 = m[ti][lane];     n2 = m[ti+2][lane+2]; }
        else if (ai < 112.5f)                 { n1 = m[ti][lane+1];   n2 = m[ti+2][lane+1]; }
        else                                  { n1 = m[ti][lane+2];   n2 = m[ti+2][lane];   }
        bool border = (i == 0) | (i == IH - 1) | (j == 0) | (j == IW - 1);
        bool keep = (c >= n1) && (c >= n2);
        float supp = keep ? c : 0.f;
        bool sb = !border && (supp >= 50.f);
        bool wb = !border && (supp >= 20.f) && !(supp >= 50.f);
        unsigned long long bs = __ballot(sb);
        unsigned long long bw = __ballot(wb);
        if (lane == 0) {
            Sp[i * 16 + bx] = bs;
            Wp[i * 16 + bx] = bw;
        }
    }
}

// =====================================================================
// Stage 4a, R8: two-round spec with EARLY-EXIT round 2.
//   Round 1: static seed, write all 32 rows (Osp + LDS Pl), publish T1.
//   Round 2: reseed with T1[j-1]; per-row compare vs Pl (the verified
//   fix convergence invariant) and STOP at first all-lane match — the
//   remaining rows are already correct from round 1. Worst case = R7.
// =====================================================================
__global__ __launch_bounds__(64, 1) void k_spec2(const unsigned int* __restrict__ Sp,
                                                 const unsigned int* __restrict__ Wp,
                                                 unsigned int* __restrict__ Osp,
                                                 unsigned int* __restrict__ flags) {
    __shared__ unsigned int Wl[32][32];   // 4 KB
    __shared__ unsigned int Sl[32][32];   // 4 KB
    __shared__ unsigned int Pl[32][32];   // 4 KB (round-1 record)
    const int lane = (int)threadIdx.x;
    const int k = lane & 31;
    const int j = (int)blockIdx.x;                     // segment 0..31
    const int r0 = j * 32 + 1;
    unsigned int* t1tok = flags;                       // 32 lines
    unsigned int* t1val = flags + 32 * FLAG_STRIDE;    // 32 lines

    #pragma unroll
    for (int q = 0; q < 16; ++q) {
        dma4(Wp + (r0 + 2 * q) * 32 + lane, &Wl[2 * q][0]);
        dma4(Sp + (r0 + 2 * q) * 32 + lane, &Sl[2 * q][0]);
    }
    unsigned int prevU = Sp[(r0 - 1) * 32 + k];        // static lower bound
    int tl = r0 + 32; if (tl > 1023) tl = 1023;
    unsigned int Stail = Sp[tl * 32 + k];
    unsigned int crp;
    CRP_FROM(prevU)
    if (j == 0 && lane < 32) Osp[k] = 0u;              // border rows
    if (j == NSEG - 1 && lane < 32) Osp[1023 * 32 + k] = 0u;
    asm volatile("s_waitcnt vmcnt(0)" ::: "memory");   // staging complete

    unsigned int SA;
    unsigned long long mloA;
    if (j == 0) {
        // true-boundary seed -> exact in one pass (R0-verified reasoning)
        SPEC_PASS(1, 0)
        if (lane < 32) AST(t1val + k, prevU);
        asm volatile("s_waitcnt vmcnt(0)" ::: "memory");
        if (lane == 0) AST(t1tok, T1_TOK);
        return;
    }
    // round 1: static seed, write Osp + Pl
    SPEC_PASS(1, 1)
    if (j < NSEG - 1) {
        if (lane < 32) AST(t1val + j * FLAG_STRIDE + k, prevU);
        asm volatile("s_waitcnt vmcnt(0)" ::: "memory");
        if (lane == 0) AST(t1tok + j * FLAG_STRIDE, T1_TOK);
    }
    // parallel exchange: seed from predecessor's round-1 tail
    {
        const unsigned int* tk = t1tok + (j - 1) * FLAG_STRIDE;
        while (ALD(tk) != T1_TOK) __builtin_amdgcn_s_sleep(1);
    }
    prevU = ALD(t1val + (j - 1) * FLAG_STRIDE + k);
    CRP_FROM(prevU)
    // round 2: recompute until convergence with round 1, then stop —
    // identical deterministic recurrence => identical remaining rows.
    SA = Sl[0][k];
    mloA = __ballot((SA & 1u) != 0u);
    #pragma unroll 1
    for (int d = 0; d < 32; ++d) {
        unsigned int Wv = Wl[d][k];
        unsigned int RS = (d < 31) ? Sl[d + 1][k] : Stail;
        unsigned long long mhiN = __ballot((RS >> 31) != 0u);
        unsigned long long mloN = __ballot((RS & 1u) != 0u);
        unsigned int rxC = SA | (SA >> 1)
                         | (((((unsigned int)(mloA >> 1)) >> k) & 1u) << 31);
        unsigned int hxN = RS | (RS << 1) | (RS >> 1)
                         | ((((unsigned int)(mhiN << 1)) >> k) & 1u)
                         | (((((unsigned int)(mloN >> 1)) >> k) & 1u) << 31);
        unsigned int Tv = rxC | hxN;
        CHAIN_STEP(Wv, SA, Tv)
        unsigned long long df = __ballot(outv != Pl[d][k]);
        if ((df & 0xFFFFFFFFull) == 0ull) break;       // converged: rest = round 1
        int r = r0 + d;
        if (r <= 1022) Osp[r * 32 + k] = outv;
        SA = RS; mloA = mloN;
    }
}

// =====================================================================
// Stage 4b+5 merged, R8: block 0 = R7-verified fix chain (Osp writes via
// LLC atomics; publishes per-chunk fixD after vmcnt drain); blocks 1..64
// = unpack consumers (R5-verified: poll fixD -> acquire-inv -> plain
// Osp reads). Producers never wait on consumers -> deadlock-free.
// =====================================================================
__global__ __launch_bounds__(1024) void k_fixup(const unsigned int* __restrict__ Sp,
                                                const unsigned int* __restrict__ Wp,
                                                unsigned int* __restrict__ Osp,
                                                float* __restrict__ out,
                                                unsigned int* __restrict__ flags) {
    __shared__ unsigned int prevLds[NW][32];
    __shared__ unsigned int locTok;
    const int tid = threadIdx.x;
    const int b = (int)blockIdx.x;
    unsigned int* fixD = flags + 80 * FLAG_STRIDE;     // 16 lines (own region)

    if (b > 0) {
        // ---------------- unpack consumer: 16 rows per block ----------------
        const int bb = b;                              // 1..64
        const unsigned int needChunk = (unsigned int)((16 * bb - 2) >> 6);
        if (tid == 0) {
            const unsigned int* f = fixD + needChunk * FLAG_STRIDE;
            while (ALD(f) != FIX_DONE)
                __builtin_amdgcn_s_sleep(8);
        }
        __syncthreads();
        __builtin_amdgcn_fence(__ATOMIC_ACQUIRE, "agent");  // inv stale lines
        const int px = ((bb - 1) * 1024 + tid) * 16;   // 16 px per thread
        unsigned int w = Osp[px >> 5];
        unsigned int bits = (w >> (px & 16)) & 0xFFFFu;
        float4* o = (float4*)(out + px);
        #pragma unroll
        for (int q = 0; q < 4; ++q) {
            float4 v;
            v.x = (bits & (1u << (4 * q + 0))) ? 1.f : 0.f;
            v.y = (bits & (1u << (4 * q + 1))) ? 1.f : 0.f;
            v.z = (bits & (1u << (4 * q + 2))) ? 1.f : 0.f;
            v.w = (bits & (1u << (4 * q + 3))) ? 1.f : 0.f;
            o[q] = v;
        }
        return;
    }

    // ---------------- block 0: serial fix chain (R7-verified) ----------------
    if (tid == 0) locTok = 0u;
    __syncthreads();
    const int wv = tid >> 6;
    const int lane = tid & 63;
    const int k = lane & 31;
    const int c = wv;
    const int r0 = c * CH + 1;

    int lr = r0 + 63; if (lr > 1022) lr = 1022;
    unsigned int p1last = Osp[lr * 32 + k];            // spec row r0+63

    if (c == 0) {
        // chunk 0 spec exact (segments 0,1 both exactly seeded)
        prevLds[1][k] = p1last;
        asm volatile("s_waitcnt lgkmcnt(0)" ::: "memory");
        if (lane == 0) *((volatile unsigned int*)&locTok) = 1u;
        if (lane == 0) AST(fixD, FIX_DONE);
        return;
    }

    // prestage depth-16 working set (overlaps predecessor chain time)
    const unsigned int* Sb = Sp + r0 * 32 + k;
    unsigned int S0 = Sb[0],    S1 = Sb[32],   S2 = Sb[64],   S3 = Sb[96],
                 S4 = Sb[128],  S5 = Sb[160],  S6 = Sb[192],  S7 = Sb[224],
                 S8 = Sb[256],  S9 = Sb[288],  S10 = Sb[320], S11 = Sb[352],
                 S12 = Sb[384], S13 = Sb[416], S14 = Sb[448], S15 = Sb[480],
                 S16 = Sb[512];
    const unsigned int* Wb = Wp + r0 * 32 + k;
    unsigned int W0 = Wb[0],    W1 = Wb[32],   W2 = Wb[64],   W3 = Wb[96],
                 W4 = Wb[128],  W5 = Wb[160],  W6 = Wb[192],  W7 = Wb[224],
                 W8 = Wb[256],  W9 = Wb[288],  W10 = Wb[320], W11 = Wb[352],
                 W12 = Wb[384], W13 = Wb[416], W14 = Wb[448], W15 = Wb[480];
    const unsigned int* Ob = Osp + r0 * 32 + k;
    unsigned int p0 = Ob[0],    p1 = Ob[32],   p2 = Ob[64],   p3 = Ob[96],
                 p4 = Ob[128],  p5 = Ob[160],  p6 = Ob[192],  p7 = Ob[224],
                 p8 = Ob[256],  p9 = Ob[288],  p10 = Ob[320], p11 = Ob[352],
                 p12 = Ob[384], p13 = Ob[416], p14 = Ob[448], p15 = Ob[480];
    unsigned int T0, T1, T2, T3, T4, T5, T6, T7,
                 T8, T9, T10, T11, T12, T13, T14, T15;
    MKT(T0, S0, S1)    MKT(T1, S1, S2)    MKT(T2, S2, S3)    MKT(T3, S3, S4)
    MKT(T4, S4, S5)    MKT(T5, S5, S6)    MKT(T6, S6, S7)    MKT(T7, S7, S8)
    MKT(T8, S8, S9)    MKT(T9, S9, S10)   MKT(T10, S10, S11) MKT(T11, S11, S12)
    MKT(T12, S12, S13) MKT(T13, S13, S14) MKT(T14, S14, S15) MKT(T15, S15, S16)

    unsigned int bd = p1last;
    bool done = false, converged = false;
    unsigned int prevU = 0u, crp = 0u;

    // token spin (verified all-LDS chain)
    while (*((volatile unsigned int*)&locTok) != (unsigned int)c)
        __builtin_amdgcn_s_sleep(1);
    asm volatile("" ::: "memory");
    prevU = prevLds[c][k];                             // true tail of chunk c-1
    CRP_FROM(prevU)
    FIX_STEP(0, W0, S0, T0, p0)      FIX_STEP(1, W1, S1, T1, p1)
    FIX_STEP(2, W2, S2, T2, p2)      FIX_STEP(3, W3, S3, T3, p3)
    FIX_STEP(4, W4, S4, T4, p4)      FIX_STEP(5, W5, S5, T5, p5)
    FIX_STEP(6, W6, S6, T6, p6)      FIX_STEP(7, W7, S7, T7, p7)
    FIX_STEP(8, W8, S8, T8, p8)      FIX_STEP(9, W9, S9, T9, p9)
    FIX_STEP(10, W10, S10, T10, p10) FIX_STEP(11, W11, S11, T11, p11)
    FIX_STEP(12, W12, S12, T12, p12) FIX_STEP(13, W13, S13, T13, p13)
    FIX_STEP(14, W14, S14, T14, p14) FIX_STEP(15, W15, S15, T15, p15)
    if (!done) {
        #pragma unroll 1
        for (int d = 16; d < CH; ++d) {                // rare deep path
            int r = r0 + d;
            if (r > 1022) break;
            unsigned int Wv = Wp[r * 32 + k];
            unsigned int Sv = Sp[r * 32 + k];
            int rn = r + 1; if (rn > 1023) rn = 1023;
            unsigned int Sn = Sp[rn * 32 + k];
            unsigned int sp = Osp[r * 32 + k];
            unsigned int Tv;
            MKT(Tv, Sv, Sn)
            CHAIN_STEP(Wv, Sv, Tv)
            unsigned long long df = __ballot(outv != sp);
            if ((df & 0xFFFFFFFFull) == 0ull) { converged = true; break; }
            AST(&Osp[r * 32 + k], outv);
        }
    }
    bd = converged ? p1last : prevU;                   // true row r0+63 either way

    // drain own stores before passing the token / publishing fixD
    asm volatile("s_waitcnt vmcnt(0)" ::: "memory");
    if (c < NW - 1) prevLds[c + 1][k] = bd;
    asm volatile("s_waitcnt lgkmcnt(0)" ::: "memory");
    if (lane == 0) *((volatile unsigned int*)&locTok) = (unsigned int)(c + 1);
    if (lane == 0) AST(fixD + c * FLAG_STRIDE, FIX_DONE);
}

extern "C" void kernel_launch(void* const* d_in, const int* in_sizes, int n_in,
                              void* d_out, int out_size, void* d_ws, size_t ws_size,
                              hipStream_t stream) {
    const float* x = (const float*)d_in[0];
    float* out = (float*)d_out;
    char* ws = (char*)d_ws;

    unsigned long long* Sp = (unsigned long long*)(ws);
    unsigned long long* Wp = (unsigned long long*)(ws + 128u * 1024u);
    unsigned int*      Osp = (unsigned int*)(ws + 256u * 1024u);
    unsigned int*      flags = (unsigned int*)(ws + 1024u * 1024u);
    // flags poisoned 0xAAAAAAAA each iteration -> "not ready"; producers
    // write T1_TOK/FIX_DONE in dependency order each launch.

    k_fused<<<1024, 256, 0, stream>>>(x, Sp, Wp);
    k_spec2<<<NSEG, 64, 0, stream>>>((const unsigned int*)Sp,
                                     (const unsigned int*)Wp, Osp, flags);
    k_fixup<<<65, 1024, 0, stream>>>((const unsigned int*)Sp,
                                     (const unsigned int*)Wp, Osp, out, flags);
}